// Round 1
// baseline (618.176 us; speedup 1.0000x reference)
//
#include <hip/hip_runtime.h>
#include <math.h>

#define B_   64
#define N_   4096
#define F_   512
#define H_   64
#define G_   10
#define PPG_ 410   // ceil(4096/10)

// ---- workspace layout (float offsets) ----
static const size_t OFF_H    = 0;                       // 16777216 : h [B,N,H]
static const size_t OFF_SC   = 16777216;                // 262144   : scores -> attn (in place)
static const size_t OFF_B1P  = OFF_SC  + 262144;        // 4096     : bn1 sum partials [blk][ch]
static const size_t OFF_B1Q  = OFF_B1P + 4096;          // 4096
static const size_t OFF_B2P  = OFF_B1Q + 4096;          // 4096
static const size_t OFF_B2Q  = OFF_B2P + 4096;          // 4096
static const size_t OFF_GRP  = OFF_B2Q + 4096;          // 40960    : grouped [B,G,H]
static const size_t OFF_Y1   = OFF_GRP + 40960;         // 262144   : conv1 raw
static const size_t OFF_RES1 = OFF_Y1  + 262144;        // 262144   : residual1
static const size_t OFF_Z1   = OFF_RES1+ 262144;        // 262144   : block1 out
static const size_t OFF_Y2   = OFF_Z1  + 262144;        // 262144   : conv2 raw
// total = 18,145,408 floats = 72.6 MB

// ============================================================================
// K1: h = x @ Wd + bd  (tile 64 rows x 64 cols, K-step 64), fused score head
// ============================================================================
__global__ __launch_bounds__(256) void k1_gemm_scores(
    const float* __restrict__ x, const float* __restrict__ Wd, const float* __restrict__ bd,
    const float* __restrict__ Wa1, const float* __restrict__ ba1,
    const float* __restrict__ Wa2, const float* __restrict__ ba2,
    float* __restrict__ h, float* __restrict__ scores)
{
    __shared__ __align__(16) float xs[64][68];   // x tile / later h tile (pad 68: bank-spread)
    __shared__ __align__(16) float wsh[64][64];  // Wd tile
    __shared__ float was[2048];                  // Wa1 [64][32]
    __shared__ float bas[32], wa2s[32], bds[64];

    const int tid = threadIdx.x;
    const int m0  = blockIdx.x * 64;

    for (int i = tid; i < 2048; i += 256) was[i] = Wa1[i];
    if (tid < 32) { bas[tid] = ba1[tid]; wa2s[tid] = Wa2[tid]; }
    if (tid < 64) bds[tid] = bd[tid];

    const int row0 = (tid >> 4) << 2;   // 0..60
    const int col0 = (tid & 15) << 2;   // 0..60
    const int lrow = tid >> 4;          // load mapping
    const int lf4  = tid & 15;

    float acc[4][4];
    #pragma unroll
    for (int r = 0; r < 4; ++r)
        #pragma unroll
        for (int c = 0; c < 4; ++c) acc[r][c] = 0.f;

    for (int kt = 0; kt < 8; ++kt) {
        const int k0 = kt * 64;
        #pragma unroll
        for (int t = 0; t < 4; ++t) {
            const int r = lrow + t * 16;
            float4 xv = *(const float4*)&x[(size_t)(m0 + r) * F_ + k0 + lf4 * 4];
            *(float4*)&xs[r][lf4 * 4] = xv;
            float4 wv = *(const float4*)&Wd[(size_t)(k0 + r) * H_ + lf4 * 4];
            *(float4*)&wsh[r][lf4 * 4] = wv;
        }
        __syncthreads();
        #pragma unroll 2
        for (int kk = 0; kk < 64; kk += 4) {
            float xa[4][4];
            #pragma unroll
            for (int r = 0; r < 4; ++r)
                *(float4*)xa[r] = *(const float4*)&xs[row0 + r][kk];
            #pragma unroll
            for (int q = 0; q < 4; ++q) {
                float4 wv = *(const float4*)&wsh[kk + q][col0];
                #pragma unroll
                for (int r = 0; r < 4; ++r) {
                    acc[r][0] += xa[r][q] * wv.x;
                    acc[r][1] += xa[r][q] * wv.y;
                    acc[r][2] += xa[r][q] * wv.z;
                    acc[r][3] += xa[r][q] * wv.w;
                }
            }
        }
        __syncthreads();
    }

    // epilogue: bias, write h, stash h tile to LDS (reuse xs)
    #pragma unroll
    for (int r = 0; r < 4; ++r) {
        float4 v;
        v.x = acc[r][0] + bds[col0 + 0];
        v.y = acc[r][1] + bds[col0 + 1];
        v.z = acc[r][2] + bds[col0 + 2];
        v.w = acc[r][3] + bds[col0 + 3];
        *(float4*)&xs[row0 + r][col0] = v;
        *(float4*)&h[(size_t)(m0 + row0 + r) * H_ + col0] = v;
    }
    __syncthreads();

    // score head: 4 threads per row, each does 8 of the 32 hidden units
    const int srow = tid >> 2;
    const int j0   = (tid & 3) * 8;
    float tac[8];
    #pragma unroll
    for (int u = 0; u < 8; ++u) tac[u] = bas[j0 + u];
    for (int k = 0; k < 64; ++k) {
        const float hv = xs[srow][k];
        #pragma unroll
        for (int u = 0; u < 8; ++u) tac[u] += hv * was[k * 32 + j0 + u];
    }
    float part = 0.f;
    #pragma unroll
    for (int u = 0; u < 8; ++u) part += tanhf(tac[u]) * wa2s[j0 + u];
    float sa = 0.f;
    const int kb = (tid & 3) * 16;
    for (int k = kb; k < kb + 16; ++k) sa += fabsf(xs[srow][k]);
    part += __shfl_xor(part, 1);
    part += __shfl_xor(part, 2);
    sa   += __shfl_xor(sa, 1);
    sa   += __shfl_xor(sa, 2);
    if ((tid & 3) == 0) {
        const float sc = part + ba2[0];
        scores[m0 + srow] = (sa > 0.f) ? sc : -1e10f;
    }
}

// ============================================================================
// K2: per-batch softmax over N; overwrite scores with attn weights
// ============================================================================
__global__ __launch_bounds__(256) void k2_softmax(float* __restrict__ scores)
{
    __shared__ float red[4], red2[4];
    const int b = blockIdx.x, tid = threadIdx.x;
    float* s = scores + (size_t)b * N_;
    float m = -3.0e38f;
    for (int i = tid; i < N_; i += 256) m = fmaxf(m, s[i]);
    #pragma unroll
    for (int o = 1; o < 64; o <<= 1) m = fmaxf(m, __shfl_xor(m, o));
    if ((tid & 63) == 0) red[tid >> 6] = m;
    __syncthreads();
    m = fmaxf(fmaxf(red[0], red[1]), fmaxf(red[2], red[3]));
    float sum = 0.f;
    for (int i = tid; i < N_; i += 256) sum += expf(s[i] - m);
    #pragma unroll
    for (int o = 1; o < 64; o <<= 1) sum += __shfl_xor(sum, o);
    if ((tid & 63) == 0) red2[tid >> 6] = sum;
    __syncthreads();
    const float inv = 1.f / (red2[0] + red2[1] + red2[2] + red2[3]);
    for (int i = tid; i < N_; i += 256) s[i] = expf(s[i] - m) * inv;
}

// ============================================================================
// K3: grouped[b,g,:] = sum_{n in group g} h[b,n,:] * attn[b,n]
// ============================================================================
__global__ __launch_bounds__(256) void k3_group(
    const float* __restrict__ h, const float* __restrict__ attn, float* __restrict__ grouped)
{
    __shared__ float red[4][64];
    const int b = blockIdx.x / G_, g = blockIdx.x % G_;
    const int n0 = g * PPG_;
    const int n1 = (n0 + PPG_ < N_) ? (n0 + PPG_) : N_;
    const int col = threadIdx.x & 63, q = threadIdx.x >> 6;
    float accv = 0.f;
    for (int n = n0 + q; n < n1; n += 4) {
        const float w = attn[(size_t)b * N_ + n];
        accv += h[(size_t)(b * N_ + n) * H_ + col] * w;
    }
    red[q][col] = accv;
    __syncthreads();
    if (q == 0)
        grouped[(b * G_ + g) * H_ + col] = red[0][col] + red[1][col] + red[2][col] + red[3][col];
}

// ============================================================================
// K4: conv1 (10->64, k=3, SAME) + residual 1x1 conv; BN1 partial sums per block
// ============================================================================
__global__ __launch_bounds__(256) void k4_conv1(
    const float* __restrict__ grouped, const float* __restrict__ c1w, const float* __restrict__ c1b,
    const float* __restrict__ r1w, const float* __restrict__ r1b,
    float* __restrict__ y1raw, float* __restrict__ res1,
    float* __restrict__ b1p, float* __restrict__ b1q)
{
    __shared__ float gs[G_][66];       // padded input (l index 1..64)
    __shared__ float cws[30 * 64];     // [i*3+k][o]
    __shared__ float rws[G_ * 64];     // [i][o]
    __shared__ float c1bs[64], r1bs[64];
    __shared__ float red[256];

    const int b = blockIdx.x, tid = threadIdx.x;
    for (int i = tid; i < G_ * 66; i += 256) {
        const int ch = i / 66, li = i % 66;
        gs[ch][li] = (li == 0 || li == 65) ? 0.f : grouped[(b * G_ + ch) * 64 + li - 1];
    }
    for (int i = tid; i < 30 * 64; i += 256) {
        const int ik = i >> 6, o = i & 63;
        cws[i] = c1w[o * 30 + ik];
    }
    for (int i = tid; i < G_ * 64; i += 256) {
        const int ch = i >> 6, o = i & 63;
        rws[i] = r1w[o * G_ + ch];
    }
    if (tid < 64) { c1bs[tid] = c1b[tid]; r1bs[tid] = r1b[tid]; }
    __syncthreads();

    const int o = tid & 63, lq = tid >> 6;
    float psum = 0.f, psq = 0.f;
    for (int s = 0; s < 16; ++s) {
        const int l = lq * 16 + s;
        float acc = c1bs[o];
        #pragma unroll
        for (int i = 0; i < G_; ++i) {
            acc += gs[i][l + 0] * cws[(i * 3 + 0) * 64 + o];
            acc += gs[i][l + 1] * cws[(i * 3 + 1) * 64 + o];
            acc += gs[i][l + 2] * cws[(i * 3 + 2) * 64 + o];
        }
        float rr = r1bs[o];
        #pragma unroll
        for (int i = 0; i < G_; ++i) rr += gs[i][l + 1] * rws[i * 64 + o];
        y1raw[(size_t)(b * 64 + o) * 64 + l] = acc;
        res1 [(size_t)(b * 64 + o) * 64 + l] = rr;
        psum += acc; psq += acc * acc;
    }
    red[tid] = psum; __syncthreads();
    if (tid < 64) b1p[b * 64 + tid] = red[tid] + red[tid + 64] + red[tid + 128] + red[tid + 192];
    __syncthreads();
    red[tid] = psq; __syncthreads();
    if (tid < 64) b1q[b * 64 + tid] = red[tid] + red[tid + 64] + red[tid + 128] + red[tid + 192];
}

// ============================================================================
// K5: finalize BN1 stats, z1 = relu(bn1(y1raw)) + res1; conv2 raw; BN2 partials
// ============================================================================
__global__ __launch_bounds__(256) void k5_conv2(
    const float* __restrict__ y1raw, const float* __restrict__ res1,
    const float* __restrict__ b1p, const float* __restrict__ b1q,
    const float* __restrict__ bn1g, const float* __restrict__ bn1b,
    const float* __restrict__ c2w, const float* __restrict__ c2b,
    float* __restrict__ z1, float* __restrict__ y2raw,
    float* __restrict__ b2p, float* __restrict__ b2q)
{
    __shared__ float zs[64][66];        // padded z1[b]
    __shared__ float c2ws[192 * 64];    // [i*3+k][o]
    __shared__ float s1[64], sh1[64], c2bs[64];
    __shared__ float red[256];

    const int b = blockIdx.x, tid = threadIdx.x;
    if (tid < 64) {
        float sm = 0.f, sq = 0.f;
        for (int blk = 0; blk < 64; ++blk) { sm += b1p[blk * 64 + tid]; sq += b1q[blk * 64 + tid]; }
        const float mean = sm * (1.f / 4096.f);
        const float var  = sq * (1.f / 4096.f) - mean * mean;
        const float sc   = bn1g[tid] * rsqrtf(var + 1e-5f);
        s1[tid] = sc; sh1[tid] = bn1b[tid] - mean * sc;
        zs[tid][0] = 0.f; zs[tid][65] = 0.f;
        c2bs[tid] = c2b[tid];
    }
    for (int i = tid; i < 192 * 64; i += 256) {
        const int ik = i >> 6, o = i & 63;
        c2ws[i] = c2w[o * 192 + ik];
    }
    __syncthreads();
    for (int i = tid; i < 4096; i += 256) {
        const int o = i >> 6, l = i & 63;
        float v = y1raw[(size_t)b * 4096 + i];
        v = fmaxf(0.f, v * s1[o] + sh1[o]) + res1[(size_t)b * 4096 + i];
        z1[(size_t)b * 4096 + i] = v;
        zs[o][1 + l] = v;
    }
    __syncthreads();

    const int o = tid & 63, lq = tid >> 6;
    float psum = 0.f, psq = 0.f;
    for (int s = 0; s < 16; ++s) {
        const int l = lq * 16 + s;
        float acc = c2bs[o];
        for (int i = 0; i < 64; ++i) {
            acc += zs[i][l + 0] * c2ws[(i * 3 + 0) * 64 + o];
            acc += zs[i][l + 1] * c2ws[(i * 3 + 1) * 64 + o];
            acc += zs[i][l + 2] * c2ws[(i * 3 + 2) * 64 + o];
        }
        y2raw[(size_t)b * 4096 + o * 64 + l] = acc;
        psum += acc; psq += acc * acc;
    }
    red[tid] = psum; __syncthreads();
    if (tid < 64) b2p[b * 64 + tid] = red[tid] + red[tid + 64] + red[tid + 128] + red[tid + 192];
    __syncthreads();
    red[tid] = psq; __syncthreads();
    if (tid < 64) b2q[b * 64 + tid] = red[tid] + red[tid + 64] + red[tid + 128] + red[tid + 192];
}

// ============================================================================
// K6: finalize BN2, y2 = relu(bn2(y2raw)) + z1; pool over L; logits
// ============================================================================
__global__ __launch_bounds__(256) void k6_final(
    const float* __restrict__ y2raw, const float* __restrict__ z1,
    const float* __restrict__ b2p, const float* __restrict__ b2q,
    const float* __restrict__ bn2g, const float* __restrict__ bn2b,
    const float* __restrict__ Wc, const float* __restrict__ bc,
    float* __restrict__ out)
{
    __shared__ float s2[64], sh2[64];
    __shared__ float red[256];
    __shared__ float pl[64];
    const int b = blockIdx.x, tid = threadIdx.x;
    if (tid < 64) {
        float sm = 0.f, sq = 0.f;
        for (int blk = 0; blk < 64; ++blk) { sm += b2p[blk * 64 + tid]; sq += b2q[blk * 64 + tid]; }
        const float mean = sm * (1.f / 4096.f);
        const float var  = sq * (1.f / 4096.f) - mean * mean;
        const float sc   = bn2g[tid] * rsqrtf(var + 1e-5f);
        s2[tid] = sc; sh2[tid] = bn2b[tid] - mean * sc;
    }
    __syncthreads();
    const int o = tid & 63, lq = tid >> 6;
    float psum = 0.f;
    for (int s = 0; s < 16; ++s) {
        const int l = lq * 16 + s;
        const size_t idx = (size_t)b * 4096 + o * 64 + l;
        psum += fmaxf(0.f, y2raw[idx] * s2[o] + sh2[o]) + z1[idx];
    }
    red[tid] = psum; __syncthreads();
    if (tid < 64) pl[tid] = (red[tid] + red[tid + 64] + red[tid + 128] + red[tid + 192]) * (1.f / 64.f);
    __syncthreads();
    if (tid < 2) {
        float lg = bc[tid];
        for (int o2 = 0; o2 < 64; ++o2) lg += pl[o2] * Wc[o2 * 2 + tid];
        out[b * 2 + tid] = lg;
    }
}

// ============================================================================
extern "C" void kernel_launch(void* const* d_in, const int* in_sizes, int n_in,
                              void* d_out, int out_size, void* d_ws, size_t ws_size,
                              hipStream_t stream)
{
    (void)in_sizes; (void)n_in; (void)out_size; (void)ws_size;
    const float* x    = (const float*)d_in[0];
    const float* Wd   = (const float*)d_in[1];
    const float* bd   = (const float*)d_in[2];
    const float* Wa1  = (const float*)d_in[3];
    const float* ba1  = (const float*)d_in[4];
    const float* Wa2  = (const float*)d_in[5];
    const float* ba2  = (const float*)d_in[6];
    const float* c1w  = (const float*)d_in[7];
    const float* c1b  = (const float*)d_in[8];
    const float* bn1g = (const float*)d_in[9];
    const float* bn1b = (const float*)d_in[10];
    const float* r1w  = (const float*)d_in[11];
    const float* r1b  = (const float*)d_in[12];
    const float* c2w  = (const float*)d_in[13];
    const float* c2b  = (const float*)d_in[14];
    const float* bn2g = (const float*)d_in[15];
    const float* bn2b = (const float*)d_in[16];
    const float* Wc   = (const float*)d_in[17];
    const float* bc   = (const float*)d_in[18];

    float* ws      = (float*)d_ws;
    float* h       = ws + OFF_H;
    float* scores  = ws + OFF_SC;
    float* b1p     = ws + OFF_B1P;
    float* b1q     = ws + OFF_B1Q;
    float* b2p     = ws + OFF_B2P;
    float* b2q     = ws + OFF_B2Q;
    float* grouped = ws + OFF_GRP;
    float* y1raw   = ws + OFF_Y1;
    float* res1    = ws + OFF_RES1;
    float* z1      = ws + OFF_Z1;
    float* y2raw   = ws + OFF_Y2;

    k1_gemm_scores<<<dim3((B_ * N_) / 64), dim3(256), 0, stream>>>(
        x, Wd, bd, Wa1, ba1, Wa2, ba2, h, scores);
    k2_softmax<<<dim3(B_), dim3(256), 0, stream>>>(scores);
    k3_group<<<dim3(B_ * G_), dim3(256), 0, stream>>>(h, scores, grouped);
    k4_conv1<<<dim3(B_), dim3(256), 0, stream>>>(grouped, c1w, c1b, r1w, r1b,
                                                 y1raw, res1, b1p, b1q);
    k5_conv2<<<dim3(B_), dim3(256), 0, stream>>>(y1raw, res1, b1p, b1q, bn1g, bn1b,
                                                 c2w, c2b, z1, y2raw, b2p, b2q);
    k6_final<<<dim3(B_), dim3(256), 0, stream>>>(y2raw, z1, b2p, b2q, bn2g, bn2b,
                                                 Wc, bc, (float*)d_out);
}